// Round 7
// baseline (4583.921 us; speedup 1.0000x reference)
//
#include <hip/hip_runtime.h>
#include <hip/hip_bf16.h>

typedef unsigned short u16;
typedef unsigned int   u32;

#define EMB   1024
#define SEQ   1024
#define HEADS 16
#define DH    64
#define BATCH 4
#define BH    64      // BATCH*HEADS
#define BS    4096    // BATCH*SEQ
#define NEG_BIG (-1.0e30f)

__device__ __forceinline__ float b2f(u16 u){ return __uint_as_float(((u32)u) << 16); }
__device__ __forceinline__ u16 f2b(float f){
    u32 u = __float_as_uint(f);
    u32 r = u + 0x7fffu + ((u >> 16) & 1u);   // round-to-nearest-even
    return (u16)(r >> 16);
}

// fp32 dual-column dot: a0 = sum_e x[e]*w[e*ws], a1 = sum_e x[e]*w[e*ws+1]
__device__ __forceinline__ void dot2_f32(const float* __restrict__ x,
                                         const float* __restrict__ w, const int ws,
                                         float& a0, float& a1)
{
    float s0 = 0.f, s1 = 0.f;
    for (int e = 0; e < EMB; e += 4) {
        const float4 xv = *(const float4*)(x + e);
        const float2 w0 = *(const float2*)(w + (size_t)(e + 0) * ws);
        const float2 w1 = *(const float2*)(w + (size_t)(e + 1) * ws);
        const float2 w2 = *(const float2*)(w + (size_t)(e + 2) * ws);
        const float2 w3 = *(const float2*)(w + (size_t)(e + 3) * ws);
        s0 += xv.x * w0.x; s1 += xv.x * w0.y;
        s0 += xv.y * w1.x; s1 += xv.y * w1.y;
        s0 += xv.z * w2.x; s1 += xv.z * w2.y;
        s0 += xv.w * w3.x; s1 += xv.w * w3.y;
    }
    a0 = s0; a1 = s1;
}

// ---------------------------------------------------------------------------
// Kernel 1 (fast path): K,V projection -> d_ws as bf16 [BH][SEQ][DH] (16 MB).
// grid (BS/8, HEADS, 2), 256 threads. blockIdx.z: 0=K, 1=V.
// ---------------------------------------------------------------------------
__global__ __launch_bounds__(256) void kv_proj(
    const float* __restrict__ Xk, const float* __restrict__ Xv,
    const float* __restrict__ Wk, const float* __restrict__ Wv,
    u16* __restrict__ Ko, u16* __restrict__ Vo)
{
    const int which = blockIdx.z;
    const float* __restrict__ X = which ? Xv : Xk;
    const float* __restrict__ W = which ? Wv : Wk;
    u16* __restrict__ Y         = which ? Vo : Ko;

    const int h   = blockIdx.y;
    const int t   = threadIdx.x;
    const int row = blockIdx.x * 8 + (t >> 5);    // [0, B*S)
    const int d0  = (t & 31) * 2;                 // [0, 64) even

    float a0, a1;
    dot2_f32(X + (size_t)row * EMB, W + (size_t)h * EMB * DH + d0, DH, a0, a1);

    const int b = row >> 10, s = row & (SEQ - 1);
    u16* yp = Y + (((size_t)(b * HEADS + h)) * SEQ + s) * DH + d0;
    yp[0] = f2b(a0); yp[1] = f2b(a1);
}

// ---------------------------------------------------------------------------
// Kernel 2: fused Q-projection + causal flash attention.
// grid (SEQ/64, BH), 256 threads. LDS = 49 KB (< 64 KB WG limit!).
// USEWS: K/V chunks from d_ws (bf16); else recomputed on the fly (zero-ws).
// CTX written to d_out as FP32, layout [b, s, h*DH+d] (concat heads).
// ---------------------------------------------------------------------------
template<bool USEWS>
__global__ __launch_bounds__(256) void attn_fused(
    const float* __restrict__ Xk, const float* __restrict__ Xv, const float* __restrict__ Xq,
    const float* __restrict__ Wk, const float* __restrict__ Wv, const float* __restrict__ Wq,
    const u16* __restrict__ Kg, const u16* __restrict__ Vg,
    float* __restrict__ CTX)
{
    __shared__ float Qs[64][DH];      // 16 KB fp32 Q tile
    __shared__ float Sp[64][65];      // 16.64 KB scores (+1 pad)
    __shared__ u16   Ks[64][DH];      // 8 KB bf16 K chunk
    __shared__ u16   Vs[64][DH];      // 8 KB bf16 V chunk
    __shared__ float rowm[64], rowl[64], rowa[64];   // 0.75 KB

    const int t  = threadIdx.x;
    const int qt = blockIdx.x;        // 0..15
    const int bh = blockIdx.y;        // 0..63
    const int b  = bh >> 4, h = bh & 15;
    const int q0 = qt * 64;
    const int r  = t >> 5;            // 0..7
    const int d0 = (t & 31) * 2;      // 0..62 even

    const size_t whead = (size_t)h * EMB * DH;

    // ---- project Q tile (64 x 64) into LDS, fp32 ----
    for (int it = 0; it < 8; ++it) {
        const int rr = it * 8 + r;
        float a0, a1;
        dot2_f32(Xq + ((size_t)(b * SEQ + q0 + rr)) * EMB, Wq + whead + d0, DH, a0, a1);
        Qs[rr][d0] = a0; Qs[rr][d0 + 1] = a1;
    }
    if (t < 64) { rowm[t] = NEG_BIG; rowl[t] = 0.f; rowa[t] = 0.f; }

    float acc[16];
    #pragma unroll
    for (int j = 0; j < 16; ++j) acc[j] = 0.f;
    const int aq  = t & 63;           // accumulator q-row
    const int ad0 = (t >> 6) * 16;    // accumulator dim base
    __syncthreads();

    for (int c = 0; c <= qt; ++c) {   // causal chunk loop
        const int k0 = c * 64;

        // ---- acquire K,V chunk (64 x 64) into LDS as bf16 ----
        if (USEWS) {
            const u32* kp = (const u32*)(Kg + ((size_t)bh * SEQ + k0) * DH);
            const u32* vp = (const u32*)(Vg + ((size_t)bh * SEQ + k0) * DH);
            u32* ks = (u32*)&Ks[0][0];
            u32* vs = (u32*)&Vs[0][0];
            #pragma unroll
            for (int i = 0; i < 8; ++i) {          // 2048 u32 / 256 threads
                const int idx = i * 256 + t;
                ks[idx] = kp[idx];
                vs[idx] = vp[idx];
            }
        } else {
            for (int it = 0; it < 8; ++it) {
                const int rr = it * 8 + r;
                const size_t xoff = ((size_t)(b * SEQ + k0 + rr)) * EMB;
                float a0, a1;
                dot2_f32(Xk + xoff, Wk + whead + d0, DH, a0, a1);
                Ks[rr][d0] = f2b(a0); Ks[rr][d0 + 1] = f2b(a1);
                dot2_f32(Xv + xoff, Wv + whead + d0, DH, a0, a1);
                Vs[rr][d0] = f2b(a0); Vs[rr][d0 + 1] = f2b(a1);
            }
        }
        __syncthreads();

        // ---- S = (Q.K^T)/32, causal mask. 4 threads per q-row ----
        {
            const int sq = t >> 2;
            const int kb = (t & 3) * 16;
            const int qg = q0 + sq;
            const float* qrow = Qs[sq];
            for (int kk = 0; kk < 16; ++kk) {
                const int k = kb + kk;
                const u16* krow = Ks[k];
                float s = 0.f;
                #pragma unroll
                for (int e = 0; e < DH; ++e) s += qrow[e] * b2f(krow[e]);
                Sp[sq][k] = (k0 + k <= qg) ? s * 0.03125f : NEG_BIG;   // 1/sqrt(1024)
            }
        }
        __syncthreads();

        // ---- online softmax, one thread per q-row ----
        if (t < 64) {
            float m = rowm[t], mnew = m;
            for (int k = 0; k < 64; ++k) { const float v = Sp[t][k]; if (v > mnew) mnew = v; }
            const float alpha = __expf(m - mnew);
            float l = rowl[t] * alpha;
            for (int k = 0; k < 64; ++k) {
                const float p = __expf(Sp[t][k] - mnew);   // masked -> 0
                Sp[t][k] = p;
                l += p;
            }
            rowm[t] = mnew; rowl[t] = l; rowa[t] = alpha;
        }
        __syncthreads();

        // ---- acc = acc*alpha + P.V ----
        {
            const float alpha = rowa[aq];
            #pragma unroll
            for (int j = 0; j < 16; ++j) acc[j] *= alpha;
            for (int k = 0; k < 64; ++k) {
                const float p = Sp[aq][k];
                const u16* vrow = &Vs[k][ad0];
                #pragma unroll
                for (int j = 0; j < 16; ++j) acc[j] += p * b2f(vrow[j]);
            }
        }
        __syncthreads();   // protect Ks/Vs/Sp before next chunk
    }

    // ---- epilogue: normalize, write CTX as FP32 into d_out ----
    const float invl = 1.f / rowl[aq];
    float* cp = CTX + ((size_t)(b * SEQ + q0 + aq)) * EMB + h * DH + ad0;
    #pragma unroll
    for (int j = 0; j < 16; ++j) cp[j] = acc[j] * invl;
}

// ---------------------------------------------------------------------------
// Kernel 3: IN-PLACE fp32 output projection + bias + ReLU on d_out.
// grid (BS/8), 256 threads. Block owns its 8 rows exclusively.
// ---------------------------------------------------------------------------
__global__ __launch_bounds__(256) void out_proj_inplace(
    float* __restrict__ OUT, const float* __restrict__ Wo, const float* __restrict__ bo)
{
    __shared__ float Xs[8][EMB];      // 32 KB

    const int t    = threadIdx.x;
    const int row0 = blockIdx.x * 8;

    // stage 8 rows (8192 fp32) into LDS
    {
        const float4* src = (const float4*)(OUT + (size_t)row0 * EMB);
        float4* dst = (float4*)&Xs[0][0];
        #pragma unroll
        for (int i = 0; i < 8; ++i) dst[i * 256 + t] = src[i * 256 + t];
    }
    __syncthreads();

    const int r  = t >> 5;            // 0..7
    const int j0 = (t & 31) * 2;
    const float* xrow = Xs[r];

    for (int jb = 0; jb < 16; ++jb) {
        const int j = jb * 64 + j0;
        float a0, a1;
        dot2_f32(xrow, Wo + j, EMB, a0, a1);
        a0 += bo[j];     if (a0 < 0.f) a0 = 0.f;
        a1 += bo[j + 1]; if (a1 < 0.f) a1 = 0.f;
        float* op = OUT + (size_t)(row0 + r) * EMB + j;
        op[0] = a0; op[1] = a1;
    }
}

// ---------------------------------------------------------------------------
extern "C" void kernel_launch(void* const* d_in, const int* in_sizes, int n_in,
                              void* d_out, int out_size, void* d_ws, size_t ws_size,
                              hipStream_t stream)
{
    const float* Xk = (const float*)d_in[0];
    const float* Xv = (const float*)d_in[1];
    const float* Xq = (const float*)d_in[2];
    const float* Wk = (const float*)d_in[3];
    const float* Wv = (const float*)d_in[4];
    const float* Wq = (const float*)d_in[5];
    const float* Wo = (const float*)d_in[6];
    const float* bo = (const float*)d_in[7];
    float* OUT = (float*)d_out;
    (void)in_sizes; (void)n_in; (void)out_size;

    // K,V staged as bf16 [BH][SEQ][DH] = 16 MB of workspace (if available).
    const size_t kv_bytes = (size_t)2 * BH * SEQ * DH * sizeof(u16);

    if (d_ws != nullptr && ws_size >= kv_bytes) {
        u16* Kw = (u16*)d_ws;
        u16* Vw = Kw + (size_t)BH * SEQ * DH;
        kv_proj<<<dim3(BS / 8, HEADS, 2), 256, 0, stream>>>(Xk, Xv, Wk, Wv, Kw, Vw);
        attn_fused<true><<<dim3(SEQ / 64, BH), 256, 0, stream>>>(
            Xk, Xv, Xq, Wk, Wv, Wq, Kw, Vw, OUT);
    } else {
        attn_fused<false><<<dim3(SEQ / 64, BH), 256, 0, stream>>>(
            Xk, Xv, Xq, Wk, Wv, Wq, nullptr, nullptr, OUT);
    }
    out_proj_inplace<<<dim3(BS / 8), 256, 0, stream>>>(OUT, Wo, bo);
}

// Round 8
// 722.034 us; speedup vs baseline: 6.3486x; 6.3486x over previous
//
#include <hip/hip_runtime.h>
#include <hip/hip_bf16.h>

typedef unsigned short u16;
typedef unsigned int   u32;
typedef __attribute__((ext_vector_type(4))) float f32x4;
typedef __attribute__((ext_vector_type(8))) short bf16x8;

#define EMB   1024
#define SEQ   1024
#define HEADS 16
#define DH    64
#define BATCH 4
#define BH    64      // BATCH*HEADS
#define BS    4096    // BATCH*SEQ
#define NEG_BIG (-1.0e30f)

__device__ __forceinline__ float b2f(u16 u){ return __uint_as_float(((u32)u) << 16); }
__device__ __forceinline__ u16 f2b(float f){
    u32 u = __float_as_uint(f);
    u32 r = u + 0x7fffu + ((u >> 16) & 1u);   // round-to-nearest-even
    return (u16)(r >> 16);
}
__device__ __forceinline__ void zero4(f32x4& v){ v[0]=0.f; v[1]=0.f; v[2]=0.f; v[3]=0.f; }

// fp32 dual-column dot (scalar fallback path only)
__device__ __forceinline__ void dot2_f32(const float* __restrict__ x,
                                         const float* __restrict__ w, const int ws,
                                         float& a0, float& a1)
{
    float s0 = 0.f, s1 = 0.f;
    for (int e = 0; e < EMB; e += 4) {
        const float4 xv = *(const float4*)(x + e);
        const float2 w0 = *(const float2*)(w + (size_t)(e + 0) * ws);
        const float2 w1 = *(const float2*)(w + (size_t)(e + 1) * ws);
        const float2 w2 = *(const float2*)(w + (size_t)(e + 2) * ws);
        const float2 w3 = *(const float2*)(w + (size_t)(e + 3) * ws);
        s0 += xv.x * w0.x; s1 += xv.x * w0.y;
        s0 += xv.y * w1.x; s1 += xv.y * w1.y;
        s0 += xv.z * w2.x; s1 += xv.z * w2.y;
        s0 += xv.w * w3.x; s1 += xv.w * w3.y;
    }
    a0 = s0; a1 = s1;
}

// ---------------------------------------------------------------------------
// Kernel 1: K,V projection via MFMA.  grid (32, 16, 2): (m-tile 128, head, K/V)
// K -> Kw [bh][s][64] bf16.  V -> Vw TRANSPOSED [bh][d][s] bf16 (PV B-operand
// layout; also makes this epilogue write contiguous).
// ---------------------------------------------------------------------------
__global__ __launch_bounds__(256) void kv_proj_mfma(
    const float* __restrict__ Xk, const float* __restrict__ Xv,
    const float* __restrict__ Wk, const float* __restrict__ Wv,
    u16* __restrict__ Kw, u16* __restrict__ Vw)
{
    __shared__ u16 As[128][64];   // X tile, m-major k-contig (16 KB)
    __shared__ u16 Bs[64][64];    // W^T tile [d][e] (8 KB)

    const int which = blockIdx.z;
    const float* __restrict__ X = which ? Xv : Xk;
    const float* __restrict__ W = which ? Wv : Wk;

    const int h    = blockIdx.y;
    const int m0   = blockIdx.x * 128;
    const int t    = threadIdx.x;
    const int wave = t >> 6, lane = t & 63;
    const int quad = lane >> 4, l16 = lane & 15;

    f32x4 acc[2][4];
    #pragma unroll
    for (int mi = 0; mi < 2; ++mi)
        #pragma unroll
        for (int ni = 0; ni < 4; ++ni) zero4(acc[mi][ni]);

    for (int k0 = 0; k0 < EMB; k0 += 64) {
        // stage A: X[m0..+127][k0..+63] fp32 -> bf16
        #pragma unroll
        for (int i = 0; i < 8; ++i) {
            const int idx = i * 256 + t;           // 0..2047
            const int r = idx >> 4, c4 = (idx & 15) * 4;
            const float4 v = *(const float4*)(X + (size_t)(m0 + r) * EMB + k0 + c4);
            u16* dst = &As[r][c4];
            dst[0] = f2b(v.x); dst[1] = f2b(v.y); dst[2] = f2b(v.z); dst[3] = f2b(v.w);
        }
        // stage B transposed: W[h][k0+e][d] -> Bs[d][e]
        #pragma unroll
        for (int i = 0; i < 4; ++i) {
            const int idx = i * 256 + t;           // 0..1023
            const int e = idx >> 4, d4 = (idx & 15) * 4;
            const float4 v = *(const float4*)(W + (size_t)h * EMB * DH + (size_t)(k0 + e) * DH + d4);
            Bs[d4 + 0][e] = f2b(v.x); Bs[d4 + 1][e] = f2b(v.y);
            Bs[d4 + 2][e] = f2b(v.z); Bs[d4 + 3][e] = f2b(v.w);
        }
        __syncthreads();

        #pragma unroll
        for (int kb = 0; kb < 2; ++kb) {
            bf16x8 bfr[4];
            #pragma unroll
            for (int ni = 0; ni < 4; ++ni)
                bfr[ni] = *(const bf16x8*)&Bs[ni * 16 + l16][kb * 32 + quad * 8];
            #pragma unroll
            for (int mi = 0; mi < 2; ++mi) {
                const bf16x8 af = *(const bf16x8*)&As[wave * 32 + mi * 16 + l16][kb * 32 + quad * 8];
                #pragma unroll
                for (int ni = 0; ni < 4; ++ni)
                    acc[mi][ni] = __builtin_amdgcn_mfma_f32_16x16x32_bf16(af, bfr[ni], acc[mi][ni], 0, 0, 0);
            }
        }
        __syncthreads();
    }

    // epilogue: C row = m0+wave*32+mi*16+quad*4+reg, col d = ni*16+l16
    const int b  = m0 >> 10;                 // 128 | 1024 -> single b per block
    const int bh = b * HEADS + h;
    #pragma unroll
    for (int mi = 0; mi < 2; ++mi) {
        const int s_base = (m0 & (SEQ - 1)) + wave * 32 + mi * 16 + quad * 4;
        #pragma unroll
        for (int ni = 0; ni < 4; ++ni) {
            const int d = ni * 16 + l16;
            if (which == 0) {               // K: [bh][s][d]
                #pragma unroll
                for (int reg = 0; reg < 4; ++reg)
                    Kw[((size_t)bh * SEQ + s_base + reg) * DH + d] = f2b(acc[mi][ni][reg]);
            } else {                        // V^T: [bh][d][s] -> 4 contiguous u16
                ushort4 pk;
                pk.x = f2b(acc[mi][ni][0]); pk.y = f2b(acc[mi][ni][1]);
                pk.z = f2b(acc[mi][ni][2]); pk.w = f2b(acc[mi][ni][3]);
                *(ushort4*)(Vw + ((size_t)bh * DH + d) * SEQ + s_base) = pk;
            }
        }
    }
}

// ---------------------------------------------------------------------------
// Kernel 2: fused Q-projection (MFMA) + causal flash attention (MFMA QK^T/PV).
// grid (16, 64): (q-tile 64, bh).  TOWS: CTX bf16 -> ws; else CTX fp32 -> OUT.
// ---------------------------------------------------------------------------
template<bool TOWS>
__global__ __launch_bounds__(256) void attn_mfma(
    const float* __restrict__ Xq, const float* __restrict__ Wq,
    const u16* __restrict__ Kw, const u16* __restrict__ Vw,
    u16* __restrict__ CTXb, float* __restrict__ CTXf)
{
    __shared__ u16 Qs[64][64];     // 8 KB, bf16 [q][d]  (A-op for QK^T)
    __shared__ u16 KsL[64][64];    // 8 KB, bf16 [s][d]  (B-op for QK^T)
    __shared__ u16 VtL[64][64];    // 8 KB, bf16 [d][s]  (B-op for PV)
    __shared__ u16 Ps[64][64];     // 8 KB, bf16 [q][k]  (A-op for PV)
    union Ov {
        struct { u16 Xs[64][64]; u16 WT[64][64]; } pro;   // 16 KB (Q-proj staging)
        float Sp[64][65];                                  // 16.25 KB (scores)
    };
    __shared__ Ov ov;
    __shared__ float rowm[64], rowl[64], rowa[64];

    const int t    = threadIdx.x;
    const int wave = t >> 6, lane = t & 63;
    const int quad = lane >> 4, l16 = lane & 15;
    const int qt = blockIdx.x, bh = blockIdx.y;
    const int b  = bh >> 4, h = bh & (HEADS - 1);
    const int q0 = qt * 64;

    // ---- Q-proj: Q[64q][64d] = X[q][1024e] x Wq[h][e][d], MFMA ----
    {
        f32x4 qacc[4];
        #pragma unroll
        for (int ni = 0; ni < 4; ++ni) zero4(qacc[ni]);

        for (int k0 = 0; k0 < EMB; k0 += 64) {
            #pragma unroll
            for (int i = 0; i < 4; ++i) {      // Xs: 64x64 fp32 -> bf16
                const int idx = i * 256 + t;
                const int r = idx >> 4, c4 = (idx & 15) * 4;
                const float4 v = *(const float4*)(Xq + (size_t)(b * SEQ + q0 + r) * EMB + k0 + c4);
                u16* dst = &ov.pro.Xs[r][c4];
                dst[0] = f2b(v.x); dst[1] = f2b(v.y); dst[2] = f2b(v.z); dst[3] = f2b(v.w);
            }
            #pragma unroll
            for (int i = 0; i < 4; ++i) {      // WT[d][e] transposed
                const int idx = i * 256 + t;
                const int e = idx >> 4, d4 = (idx & 15) * 4;
                const float4 v = *(const float4*)(Wq + (size_t)h * EMB * DH + (size_t)(k0 + e) * DH + d4);
                ov.pro.WT[d4 + 0][e] = f2b(v.x); ov.pro.WT[d4 + 1][e] = f2b(v.y);
                ov.pro.WT[d4 + 2][e] = f2b(v.z); ov.pro.WT[d4 + 3][e] = f2b(v.w);
            }
            __syncthreads();
            #pragma unroll
            for (int kb = 0; kb < 2; ++kb) {
                const bf16x8 af = *(const bf16x8*)&ov.pro.Xs[wave * 16 + l16][kb * 32 + quad * 8];
                #pragma unroll
                for (int ni = 0; ni < 4; ++ni) {
                    const bf16x8 bf = *(const bf16x8*)&ov.pro.WT[ni * 16 + l16][kb * 32 + quad * 8];
                    qacc[ni] = __builtin_amdgcn_mfma_f32_16x16x32_bf16(af, bf, qacc[ni], 0, 0, 0);
                }
            }
            __syncthreads();
        }
        // write Q to LDS bf16 (C layout: row=q, col=d)
        #pragma unroll
        for (int ni = 0; ni < 4; ++ni)
            #pragma unroll
            for (int reg = 0; reg < 4; ++reg)
                Qs[wave * 16 + quad * 4 + reg][ni * 16 + l16] = f2b(qacc[ni][reg]);
    }
    if (t < 64) { rowm[t] = NEG_BIG; rowl[t] = 0.f; rowa[t] = 0.f; }

    f32x4 oacc[4];
    #pragma unroll
    for (int ni = 0; ni < 4; ++ni) zero4(oacc[ni]);
    __syncthreads();

    // ---- causal chunk loop ----
    for (int c = 0; c <= qt; ++c) {
        const int k0 = c * 64;

        #pragma unroll
        for (int i = 0; i < 4; ++i) {          // stage K chunk [s][d]
            const int idx = i * 256 + t;
            const int r = idx >> 4, c4 = (idx & 15) * 4;
            *(ushort4*)&KsL[r][c4] = *(const ushort4*)(Kw + ((size_t)bh * SEQ + k0 + r) * DH + c4);
        }
        #pragma unroll
        for (int i = 0; i < 4; ++i) {          // stage V^T chunk [d][s]
            const int idx = i * 256 + t;
            const int r = idx >> 4, c4 = (idx & 15) * 4;
            *(ushort4*)&VtL[r][c4] = *(const ushort4*)(Vw + ((size_t)bh * DH + r) * SEQ + k0 + c4);
        }
        __syncthreads();

        // ---- S = Q.K^T (MFMA), wave -> q rows [wave*16, +16) ----
        {
            f32x4 sacc[4];
            #pragma unroll
            for (int ni = 0; ni < 4; ++ni) zero4(sacc[ni]);
            #pragma unroll
            for (int kb = 0; kb < 2; ++kb) {
                const bf16x8 af = *(const bf16x8*)&Qs[wave * 16 + l16][kb * 32 + quad * 8];
                #pragma unroll
                for (int ni = 0; ni < 4; ++ni) {
                    const bf16x8 bf = *(const bf16x8*)&KsL[ni * 16 + l16][kb * 32 + quad * 8];
                    sacc[ni] = __builtin_amdgcn_mfma_f32_16x16x32_bf16(af, bf, sacc[ni], 0, 0, 0);
                }
            }
            #pragma unroll
            for (int ni = 0; ni < 4; ++ni)
                #pragma unroll
                for (int reg = 0; reg < 4; ++reg)
                    ov.Sp[wave * 16 + quad * 4 + reg][ni * 16 + l16] = sacc[ni][reg];
        }
        __syncthreads();

        // ---- online softmax, one thread per q-row (rotated k for banks) ----
        if (t < 64) {
            const int qg = q0 + t;
            float m = rowm[t], mnew = m;
            for (int i = 0; i < 64; ++i) {
                const int k = (i + t) & 63;
                const float v = (k0 + k <= qg) ? ov.Sp[t][k] * 0.03125f : NEG_BIG;
                ov.Sp[t][k] = v;
                if (v > mnew) mnew = v;
            }
            const float alpha = __expf(m - mnew);
            float l = rowl[t] * alpha;
            for (int i = 0; i < 64; ++i) {
                const int k = (i + t) & 63;
                const float p = __expf(ov.Sp[t][k] - mnew);
                Ps[t][k] = f2b(p);
                l += p;
            }
            rowm[t] = mnew; rowl[t] = l; rowa[t] = alpha;
        }
        __syncthreads();

        // ---- O = O*alpha + P.V (MFMA) ----
        {
            float alr[4];
            #pragma unroll
            for (int reg = 0; reg < 4; ++reg) alr[reg] = rowa[wave * 16 + quad * 4 + reg];
            #pragma unroll
            for (int ni = 0; ni < 4; ++ni)
                #pragma unroll
                for (int reg = 0; reg < 4; ++reg) oacc[ni][reg] *= alr[reg];
            #pragma unroll
            for (int kb = 0; kb < 2; ++kb) {
                const bf16x8 af = *(const bf16x8*)&Ps[wave * 16 + l16][kb * 32 + quad * 8];
                #pragma unroll
                for (int ni = 0; ni < 4; ++ni) {
                    const bf16x8 bf = *(const bf16x8*)&VtL[ni * 16 + l16][kb * 32 + quad * 8];
                    oacc[ni] = __builtin_amdgcn_mfma_f32_16x16x32_bf16(af, bf, oacc[ni], 0, 0, 0);
                }
            }
        }
        __syncthreads();   // protect K/V/P/Sp + rowa before next chunk
    }

    // ---- epilogue: normalize, write CTX ----
    float ilr[4];
    #pragma unroll
    for (int reg = 0; reg < 4; ++reg) ilr[reg] = 1.f / rowl[wave * 16 + quad * 4 + reg];
    #pragma unroll
    for (int ni = 0; ni < 4; ++ni) {
        const int d = ni * 16 + l16;
        #pragma unroll
        for (int reg = 0; reg < 4; ++reg) {
            const int q = wave * 16 + quad * 4 + reg;
            const float val = oacc[ni][reg] * ilr[reg];
            const size_t off = ((size_t)(b * SEQ + q0 + q)) * EMB + h * DH + d;
            if (TOWS) CTXb[off] = f2b(val);
            else      CTXf[off] = val;
        }
    }
}

// ---------------------------------------------------------------------------
// Kernel 3a (fast): out-projection via MFMA. CTX bf16 (ws) x Wo -> OUT fp32.
// grid (32, 16): (m-tile 128, n-tile 64).  + bias + ReLU.
// ---------------------------------------------------------------------------
__global__ __launch_bounds__(256) void out_proj_mfma(
    const u16* __restrict__ CTXb, const float* __restrict__ Wo,
    const float* __restrict__ bo, float* __restrict__ OUT)
{
    __shared__ u16 As[128][64];
    __shared__ u16 Bs[64][64];

    const int m0 = blockIdx.x * 128;
    const int n0 = blockIdx.y * 64;
    const int t = threadIdx.x;
    const int wave = t >> 6, lane = t & 63;
    const int quad = lane >> 4, l16 = lane & 15;

    f32x4 acc[2][4];
    #pragma unroll
    for (int mi = 0; mi < 2; ++mi)
        #pragma unroll
        for (int ni = 0; ni < 4; ++ni) zero4(acc[mi][ni]);

    for (int k0 = 0; k0 < EMB; k0 += 64) {
        #pragma unroll
        for (int i = 0; i < 8; ++i) {          // A: bf16 direct copy
            const int idx = i * 256 + t;
            const int r = idx >> 4, c4 = (idx & 15) * 4;
            *(ushort4*)&As[r][c4] = *(const ushort4*)(CTXb + (size_t)(m0 + r) * EMB + k0 + c4);
        }
        #pragma unroll
        for (int i = 0; i < 4; ++i) {          // B: Wo[k0+e][n0+j] -> Bs[j][e]
            const int idx = i * 256 + t;
            const int e = idx >> 4, j4 = (idx & 15) * 4;
            const float4 v = *(const float4*)(Wo + (size_t)(k0 + e) * EMB + n0 + j4);
            Bs[j4 + 0][e] = f2b(v.x); Bs[j4 + 1][e] = f2b(v.y);
            Bs[j4 + 2][e] = f2b(v.z); Bs[j4 + 3][e] = f2b(v.w);
        }
        __syncthreads();
        #pragma unroll
        for (int kb = 0; kb < 2; ++kb) {
            bf16x8 bfr[4];
            #pragma unroll
            for (int ni = 0; ni < 4; ++ni)
                bfr[ni] = *(const bf16x8*)&Bs[ni * 16 + l16][kb * 32 + quad * 8];
            #pragma unroll
            for (int mi = 0; mi < 2; ++mi) {
                const bf16x8 af = *(const bf16x8*)&As[wave * 32 + mi * 16 + l16][kb * 32 + quad * 8];
                #pragma unroll
                for (int ni = 0; ni < 4; ++ni)
                    acc[mi][ni] = __builtin_amdgcn_mfma_f32_16x16x32_bf16(af, bfr[ni], acc[mi][ni], 0, 0, 0);
            }
        }
        __syncthreads();
    }

    #pragma unroll
    for (int mi = 0; mi < 2; ++mi) {
        const int row = m0 + wave * 32 + mi * 16 + quad * 4;
        #pragma unroll
        for (int ni = 0; ni < 4; ++ni) {
            const int col = n0 + ni * 16 + l16;
            const float bias = bo[col];
            #pragma unroll
            for (int reg = 0; reg < 4; ++reg) {
                float v = acc[mi][ni][reg] + bias;
                if (v < 0.f) v = 0.f;
                OUT[(size_t)(row + reg) * EMB + col] = v;
            }
        }
    }
}

// ---------------------------------------------------------------------------
// Kernel 3b (fallback, R7-proven): in-place scalar out-proj on d_out fp32.
// ---------------------------------------------------------------------------
__global__ __launch_bounds__(256) void out_proj_inplace(
    float* __restrict__ OUT, const float* __restrict__ Wo, const float* __restrict__ bo)
{
    __shared__ float Xs[8][EMB];

    const int t    = threadIdx.x;
    const int row0 = blockIdx.x * 8;
    {
        const float4* src = (const float4*)(OUT + (size_t)row0 * EMB);
        float4* dst = (float4*)&Xs[0][0];
        #pragma unroll
        for (int i = 0; i < 8; ++i) dst[i * 256 + t] = src[i * 256 + t];
    }
    __syncthreads();

    const int r  = t >> 5;
    const int j0 = (t & 31) * 2;
    const float* xrow = Xs[r];
    for (int jb = 0; jb < 16; ++jb) {
        const int j = jb * 64 + j0;
        float a0, a1;
        dot2_f32(xrow, Wo + j, EMB, a0, a1);
        a0 += bo[j];     if (a0 < 0.f) a0 = 0.f;
        a1 += bo[j + 1]; if (a1 < 0.f) a1 = 0.f;
        float* op = OUT + (size_t)(row0 + r) * EMB + j;
        op[0] = a0; op[1] = a1;
    }
}

// ---------------------------------------------------------------------------
extern "C" void kernel_launch(void* const* d_in, const int* in_sizes, int n_in,
                              void* d_out, int out_size, void* d_ws, size_t ws_size,
                              hipStream_t stream)
{
    const float* Xk = (const float*)d_in[0];
    const float* Xv = (const float*)d_in[1];
    const float* Xq = (const float*)d_in[2];
    const float* Wk = (const float*)d_in[3];
    const float* Wv = (const float*)d_in[4];
    const float* Wq = (const float*)d_in[5];
    const float* Wo = (const float*)d_in[6];
    const float* bo = (const float*)d_in[7];
    float* OUT = (float*)d_out;
    (void)in_sizes; (void)n_in; (void)out_size;

    const size_t kv_elems  = (size_t)BH * SEQ * DH;           // per K or V
    const size_t kv_bytes  = 2 * kv_elems * sizeof(u16);      // 16 MB
    const size_t ctx_bytes = (size_t)BS * EMB * sizeof(u16);  // 8 MB

    u16* Kw = (u16*)d_ws;
    u16* Vw = Kw + kv_elems;

    kv_proj_mfma<<<dim3(32, HEADS, 2), 256, 0, stream>>>(Xk, Xv, Wk, Wv, Kw, Vw);

    if (ws_size >= kv_bytes + ctx_bytes) {
        u16* CTXb = Vw + kv_elems;
        attn_mfma<true><<<dim3(SEQ / 64, BH), 256, 0, stream>>>(Xq, Wq, Kw, Vw, CTXb, nullptr);
        out_proj_mfma<<<dim3(32, EMB / 64), 256, 0, stream>>>(CTXb, Wo, bo, OUT);
    } else {
        attn_mfma<false><<<dim3(SEQ / 64, BH), 256, 0, stream>>>(Xq, Wq, Kw, Vw, nullptr, OUT);
        out_proj_inplace<<<dim3(BS / 8), 256, 0, stream>>>(OUT, Wo, bo);
    }
}

// Round 9
// 359.249 us; speedup vs baseline: 12.7597x; 2.0098x over previous
//
#include <hip/hip_runtime.h>
#include <hip/hip_bf16.h>

typedef unsigned short u16;
typedef unsigned int   u32;
typedef __attribute__((ext_vector_type(4))) float f32x4;
typedef __attribute__((ext_vector_type(8))) short bf16x8;

#define EMB   1024
#define SEQ   1024
#define HEADS 16
#define DH    64
#define BATCH 4
#define BH    64      // BATCH*HEADS
#define BS    4096    // BATCH*SEQ
#define LDP   72      // padded LDS row (u16): 144 B = 36 banks -> conflict-free MFMA reads
#define NEG_BIG (-1.0e30f)

__device__ __forceinline__ float b2f(u16 u){ return __uint_as_float(((u32)u) << 16); }
__device__ __forceinline__ u16 f2b(float f){
    u32 u = __float_as_uint(f);
    u32 r = u + 0x7fffu + ((u >> 16) & 1u);   // round-to-nearest-even
    return (u16)(r >> 16);
}
__device__ __forceinline__ void zero4(f32x4& v){ v[0]=0.f; v[1]=0.f; v[2]=0.f; v[3]=0.f; }
__device__ __forceinline__ ushort4 pk4(float a, float b, float c, float d){
    ushort4 p; p.x = f2b(a); p.y = f2b(b); p.z = f2b(c); p.w = f2b(d); return p;
}

// fp32 dual-column dot (scalar fallback path only)
__device__ __forceinline__ void dot2_f32(const float* __restrict__ x,
                                         const float* __restrict__ w, const int ws,
                                         float& a0, float& a1)
{
    float s0 = 0.f, s1 = 0.f;
    for (int e = 0; e < EMB; e += 4) {
        const float4 xv = *(const float4*)(x + e);
        const float2 w0 = *(const float2*)(w + (size_t)(e + 0) * ws);
        const float2 w1 = *(const float2*)(w + (size_t)(e + 1) * ws);
        const float2 w2 = *(const float2*)(w + (size_t)(e + 2) * ws);
        const float2 w3 = *(const float2*)(w + (size_t)(e + 3) * ws);
        s0 += xv.x * w0.x; s1 += xv.x * w0.y;
        s0 += xv.y * w1.x; s1 += xv.y * w1.y;
        s0 += xv.z * w2.x; s1 += xv.z * w2.y;
        s0 += xv.w * w3.x; s1 += xv.w * w3.y;
    }
    a0 = s0; a1 = s1;
}

// ---------------------------------------------------------------------------
// Kernel 1: Q/K/V projection via MFMA. grid (32, 16, z): (m-tile 128, head, which)
// which: 0 -> Kw [bh][s][64], 1 -> Vw TRANSPOSED [bh][d][s], 2 -> Qw [bh][s][64]
// ---------------------------------------------------------------------------
__global__ __launch_bounds__(256) void qkv_proj_mfma(
    const float* __restrict__ Xk, const float* __restrict__ Xv, const float* __restrict__ Xq,
    const float* __restrict__ Wk, const float* __restrict__ Wv, const float* __restrict__ Wq,
    u16* __restrict__ Kw, u16* __restrict__ Vw, u16* __restrict__ Qw)
{
    __shared__ u16 As[128][LDP];   // X tile m-major (18.4 KB)
    __shared__ u16 Bs[64][LDP];    // W^T tile [d][e] (9.2 KB)

    const int which = blockIdx.z;
    const float* __restrict__ X = (which == 0) ? Xk : (which == 1) ? Xv : Xq;
    const float* __restrict__ W = (which == 0) ? Wk : (which == 1) ? Wv : Wq;

    const int h    = blockIdx.y;
    const int m0   = blockIdx.x * 128;
    const int t    = threadIdx.x;
    const int wave = t >> 6, lane = t & 63;
    const int quad = lane >> 4, l16 = lane & 15;

    f32x4 acc[2][4];
    #pragma unroll
    for (int mi = 0; mi < 2; ++mi)
        #pragma unroll
        for (int ni = 0; ni < 4; ++ni) zero4(acc[mi][ni]);

    const size_t wbase = (size_t)h * EMB * DH;
    for (int k0 = 0; k0 < EMB; k0 += 64) {
        // stage A: X[m0..+127][k0..+63] fp32 -> bf16
        #pragma unroll
        for (int i = 0; i < 8; ++i) {
            const int idx = i * 256 + t;           // 0..2047
            const int r = idx >> 4, c4 = (idx & 15) * 4;
            const float4 v = *(const float4*)(X + (size_t)(m0 + r) * EMB + k0 + c4);
            *(ushort4*)&As[r][c4] = pk4(v.x, v.y, v.z, v.w);
        }
        // stage B^T: Bs[d][e] <- W[h][k0+e][d], strided-dword reads, 8B packed writes
        #pragma unroll
        for (int i = 0; i < 4; ++i) {
            const int d  = t & 63;
            const int e0 = (t >> 6) * 4 + i * 16;
            const float v0 = W[wbase + (size_t)(k0 + e0 + 0) * DH + d];
            const float v1 = W[wbase + (size_t)(k0 + e0 + 1) * DH + d];
            const float v2 = W[wbase + (size_t)(k0 + e0 + 2) * DH + d];
            const float v3 = W[wbase + (size_t)(k0 + e0 + 3) * DH + d];
            *(ushort4*)&Bs[d][e0] = pk4(v0, v1, v2, v3);
        }
        __syncthreads();

        #pragma unroll
        for (int kb = 0; kb < 2; ++kb) {
            bf16x8 bfr[4];
            #pragma unroll
            for (int ni = 0; ni < 4; ++ni)
                bfr[ni] = *(const bf16x8*)&Bs[ni * 16 + l16][kb * 32 + quad * 8];
            #pragma unroll
            for (int mi = 0; mi < 2; ++mi) {
                const bf16x8 af = *(const bf16x8*)&As[wave * 32 + mi * 16 + l16][kb * 32 + quad * 8];
                #pragma unroll
                for (int ni = 0; ni < 4; ++ni)
                    acc[mi][ni] = __builtin_amdgcn_mfma_f32_16x16x32_bf16(af, bfr[ni], acc[mi][ni], 0, 0, 0);
            }
        }
        __syncthreads();
    }

    // epilogue: C row = m0+wave*32+mi*16+quad*4+reg, col d = ni*16+l16
    const int b  = m0 >> 10;
    const int bh = b * HEADS + h;
    u16* __restrict__ RowDst = (which == 0) ? Kw : Qw;
    #pragma unroll
    for (int mi = 0; mi < 2; ++mi) {
        const int s_base = (m0 & (SEQ - 1)) + wave * 32 + mi * 16 + quad * 4;
        #pragma unroll
        for (int ni = 0; ni < 4; ++ni) {
            const int d = ni * 16 + l16;
            if (which != 1) {               // K or Q: [bh][s][d]
                #pragma unroll
                for (int reg = 0; reg < 4; ++reg)
                    RowDst[((size_t)bh * SEQ + s_base + reg) * DH + d] = f2b(acc[mi][ni][reg]);
            } else {                        // V^T: [bh][d][s] -> contiguous 4
                *(ushort4*)(Vw + ((size_t)bh * DH + d) * SEQ + s_base) =
                    pk4(acc[mi][ni][0], acc[mi][ni][1], acc[mi][ni][2], acc[mi][ni][3]);
            }
        }
    }
}

// ---------------------------------------------------------------------------
// Kernel 2: causal flash attention, MFMA QK^T/PV, register online-softmax.
// grid (16, 64): (q-tile 64, bh). Each wave owns 16 q-rows end-to-end.
// QWS: Q bf16 from ws; else projected in-kernel from Xq/Wq.
// TOWS: CTX bf16 -> ws; else CTX fp32 -> d_out.
// ---------------------------------------------------------------------------
template<bool QWS, bool TOWS>
__global__ __launch_bounds__(256) void attn_flash(
    const float* __restrict__ Xq, const float* __restrict__ Wq,
    const u16* __restrict__ Qg, const u16* __restrict__ Kg, const u16* __restrict__ Vg,
    u16* __restrict__ CTXb, float* __restrict__ CTXf)
{
    __shared__ u16 Qs[64][LDP];
    union KVU {
        struct { u16 Ks[64][LDP]; u16 Vt[64][LDP]; } kv;
        struct { u16 Xs[64][LDP]; u16 WT[64][LDP]; } pr;   // Q-proj staging (QWS=false)
    };
    __shared__ KVU uu;
    __shared__ u16 Ps[64][LDP];

    const int t    = threadIdx.x;
    const int wave = t >> 6, lane = t & 63;
    const int quad = lane >> 4, l16 = lane & 15;
    const int qt = blockIdx.x, bh = blockIdx.y;
    const int b  = bh >> 4, h = bh & (HEADS - 1);
    const int q0 = qt * 64;

    // ---- acquire Q tile (64 x 64 bf16) into Qs ----
    if (QWS) {
        #pragma unroll
        for (int i = 0; i < 4; ++i) {
            const int idx = i * 256 + t;
            const int r = idx >> 4, c4 = (idx & 15) * 4;
            *(ushort4*)&Qs[r][c4] = *(const ushort4*)(Qg + ((size_t)bh * SEQ + q0 + r) * DH + c4);
        }
    } else {
        f32x4 qacc[4];
        #pragma unroll
        for (int ni = 0; ni < 4; ++ni) zero4(qacc[ni]);
        const size_t wbase = (size_t)h * EMB * DH;
        for (int k0 = 0; k0 < EMB; k0 += 64) {
            #pragma unroll
            for (int i = 0; i < 4; ++i) {
                const int idx = i * 256 + t;
                const int r = idx >> 4, c4 = (idx & 15) * 4;
                const float4 v = *(const float4*)(Xq + (size_t)(b * SEQ + q0 + r) * EMB + k0 + c4);
                *(ushort4*)&uu.pr.Xs[r][c4] = pk4(v.x, v.y, v.z, v.w);
            }
            #pragma unroll
            for (int i = 0; i < 4; ++i) {
                const int d  = t & 63;
                const int e0 = (t >> 6) * 4 + i * 16;
                const float v0 = Wq[wbase + (size_t)(k0 + e0 + 0) * DH + d];
                const float v1 = Wq[wbase + (size_t)(k0 + e0 + 1) * DH + d];
                const float v2 = Wq[wbase + (size_t)(k0 + e0 + 2) * DH + d];
                const float v3 = Wq[wbase + (size_t)(k0 + e0 + 3) * DH + d];
                *(ushort4*)&uu.pr.WT[d][e0] = pk4(v0, v1, v2, v3);
            }
            __syncthreads();
            #pragma unroll
            for (int kb = 0; kb < 2; ++kb) {
                const bf16x8 af = *(const bf16x8*)&uu.pr.Xs[wave * 16 + l16][kb * 32 + quad * 8];
                #pragma unroll
                for (int ni = 0; ni < 4; ++ni) {
                    const bf16x8 bf = *(const bf16x8*)&uu.pr.WT[ni * 16 + l16][kb * 32 + quad * 8];
                    qacc[ni] = __builtin_amdgcn_mfma_f32_16x16x32_bf16(af, bf, qacc[ni], 0, 0, 0);
                }
            }
            __syncthreads();
        }
        #pragma unroll
        for (int ni = 0; ni < 4; ++ni)
            #pragma unroll
            for (int reg = 0; reg < 4; ++reg)
                Qs[wave * 16 + quad * 4 + reg][ni * 16 + l16] = f2b(qacc[ni][reg]);
    }

    // per-lane online-softmax state for this wave's 16 rows (row = quad*4+reg)
    float m[4], l[4];
    #pragma unroll
    for (int reg = 0; reg < 4; ++reg) { m[reg] = NEG_BIG; l[reg] = 0.f; }
    f32x4 oacc[4];
    #pragma unroll
    for (int ni = 0; ni < 4; ++ni) zero4(oacc[ni]);
    __syncthreads();

    // ---- causal chunk loop ----
    for (int c = 0; c <= qt; ++c) {
        const int k0 = c * 64;

        #pragma unroll
        for (int i = 0; i < 4; ++i) {          // K chunk [s][d]
            const int idx = i * 256 + t;
            const int r = idx >> 4, c4 = (idx & 15) * 4;
            *(ushort4*)&uu.kv.Ks[r][c4] = *(const ushort4*)(Kg + ((size_t)bh * SEQ + k0 + r) * DH + c4);
        }
        #pragma unroll
        for (int i = 0; i < 4; ++i) {          // V^T chunk [d][s]
            const int idx = i * 256 + t;
            const int r = idx >> 4, c4 = (idx & 15) * 4;
            *(ushort4*)&uu.kv.Vt[r][c4] = *(const ushort4*)(Vg + ((size_t)bh * DH + r) * SEQ + k0 + c4);
        }
        __syncthreads();

        // ---- S = Q.K^T (MFMA); wave covers q-rows [wave*16, +16) x 64 k ----
        f32x4 sacc[4];
        #pragma unroll
        for (int ni = 0; ni < 4; ++ni) zero4(sacc[ni]);
        #pragma unroll
        for (int kb = 0; kb < 2; ++kb) {
            const bf16x8 af = *(const bf16x8*)&Qs[wave * 16 + l16][kb * 32 + quad * 8];
            #pragma unroll
            for (int ni = 0; ni < 4; ++ni) {
                const bf16x8 bf = *(const bf16x8*)&uu.kv.Ks[ni * 16 + l16][kb * 32 + quad * 8];
                sacc[ni] = __builtin_amdgcn_mfma_f32_16x16x32_bf16(af, bf, sacc[ni], 0, 0, 0);
            }
        }

        // ---- register online softmax (rows owned per-lane; shuffle over 16) ----
        const bool diag = (c == qt);
        #pragma unroll
        for (int reg = 0; reg < 4; ++reg) {
            const int rloc = quad * 4 + reg;          // local row in wave tile
            float sv[4];
            #pragma unroll
            for (int ni = 0; ni < 4; ++ni) {
                float s = sacc[ni][reg] * 0.03125f;   // 1/sqrt(1024)
                if (diag && (ni * 16 + l16 > wave * 16 + rloc)) s = NEG_BIG;
                sv[ni] = s;
            }
            float mx = fmaxf(fmaxf(sv[0], sv[1]), fmaxf(sv[2], sv[3]));
            mx = fmaxf(mx, m[reg]);
            #pragma unroll
            for (int off = 1; off < 16; off <<= 1) mx = fmaxf(mx, __shfl_xor(mx, off));
            const float alpha = __expf(m[reg] - mx);
            float rs = 0.f;
            #pragma unroll
            for (int ni = 0; ni < 4; ++ni) {
                const float p = __expf(sv[ni] - mx);
                Ps[wave * 16 + rloc][ni * 16 + l16] = f2b(p);
                rs += p;
            }
            #pragma unroll
            for (int off = 1; off < 16; off <<= 1) rs += __shfl_xor(rs, off);
            l[reg] = l[reg] * alpha + rs;
            m[reg] = mx;
            #pragma unroll
            for (int ni = 0; ni < 4; ++ni) oacc[ni][reg] *= alpha;
        }
        __syncthreads();

        // ---- O += P.V (MFMA) ----
        #pragma unroll
        for (int kb = 0; kb < 2; ++kb) {
            const bf16x8 af = *(const bf16x8*)&Ps[wave * 16 + l16][kb * 32 + quad * 8];
            #pragma unroll
            for (int ni = 0; ni < 4; ++ni) {
                const bf16x8 bf = *(const bf16x8*)&uu.kv.Vt[ni * 16 + l16][kb * 32 + quad * 8];
                oacc[ni] = __builtin_amdgcn_mfma_f32_16x16x32_bf16(af, bf, oacc[ni], 0, 0, 0);
            }
        }
        __syncthreads();   // protect Ks/Vt/Ps before next chunk
    }

    // ---- epilogue: normalize, write CTX [b,s,h*64+d] ----
    float il[4];
    #pragma unroll
    for (int reg = 0; reg < 4; ++reg) il[reg] = 1.f / l[reg];
    #pragma unroll
    for (int ni = 0; ni < 4; ++ni) {
        const int d = ni * 16 + l16;
        #pragma unroll
        for (int reg = 0; reg < 4; ++reg) {
            const int q = wave * 16 + quad * 4 + reg;
            const float val = oacc[ni][reg] * il[reg];
            const size_t off = ((size_t)(b * SEQ + q0 + q)) * EMB + h * DH + d;
            if (TOWS) CTXb[off] = f2b(val);
            else      CTXf[off] = val;
        }
    }
}

// ---------------------------------------------------------------------------
// Kernel 3a: out-projection MFMA. CTX bf16 (ws) x Wo(->bf16) + bo, ReLU -> OUT fp32.
// grid (32, 16): (m-tile 128, n-tile 64).
// ---------------------------------------------------------------------------
__global__ __launch_bounds__(256) void out_proj_mfma(
    const u16* __restrict__ CTXb, const float* __restrict__ Wo,
    const float* __restrict__ bo, float* __restrict__ OUT)
{
    __shared__ u16 As[128][LDP];
    __shared__ u16 Bs[64][LDP];

    const int m0 = blockIdx.x * 128;
    const int n0 = blockIdx.y * 64;
    const int t = threadIdx.x;
    const int wave = t >> 6, lane = t & 63;
    const int quad = lane >> 4, l16 = lane & 15;

    f32x4 acc[2][4];
    #pragma unroll
    for (int mi = 0; mi < 2; ++mi)
        #pragma unroll
        for (int ni = 0; ni < 4; ++ni) zero4(acc[mi][ni]);

    for (int k0 = 0; k0 < EMB; k0 += 64) {
        #pragma unroll
        for (int i = 0; i < 8; ++i) {          // A: bf16 copy
            const int idx = i * 256 + t;
            const int r = idx >> 4, c4 = (idx & 15) * 4;
            *(ushort4*)&As[r][c4] = *(const ushort4*)(CTXb + (size_t)(m0 + r) * EMB + k0 + c4);
        }
        #pragma unroll
        for (int i = 0; i < 4; ++i) {          // B^T: Bs[j][e] <- Wo[k0+e][n0+j]
            const int d  = t & 63;
            const int e0 = (t >> 6) * 4 + i * 16;
            const float v0 = Wo[(size_t)(k0 + e0 + 0) * EMB + n0 + d];
            const float v1 = Wo[(size_t)(k0 + e0 + 1) * EMB + n0 + d];
            const float v2 = Wo[(size_t)(k0 + e0 + 2) * EMB + n0 + d];
            const float v3 = Wo[(size_t)(k0 + e0 + 3) * EMB + n0 + d];
            *(ushort4*)&Bs[d][e0] = pk4(v0, v1, v2, v3);
        }
        __syncthreads();
        #pragma unroll
        for (int kb = 0; kb < 2; ++kb) {
            bf16x8 bfr[4];
            #pragma unroll
            for (int ni = 0; ni < 4; ++ni)
                bfr[ni] = *(const bf16x8*)&Bs[ni * 16 + l16][kb * 32 + quad * 8];
            #pragma unroll
            for (int mi = 0; mi < 2; ++mi) {
                const bf16x8 af = *(const bf16x8*)&As[wave * 32 + mi * 16 + l16][kb * 32 + quad * 8];
                #pragma unroll
                for (int ni = 0; ni < 4; ++ni)
                    acc[mi][ni] = __builtin_amdgcn_mfma_f32_16x16x32_bf16(af, bfr[ni], acc[mi][ni], 0, 0, 0);
            }
        }
        __syncthreads();
    }

    #pragma unroll
    for (int mi = 0; mi < 2; ++mi) {
        const int row = m0 + wave * 32 + mi * 16 + quad * 4;
        #pragma unroll
        for (int ni = 0; ni < 4; ++ni) {
            const int col = n0 + ni * 16 + l16;
            const float bias = bo[col];
            #pragma unroll
            for (int reg = 0; reg < 4; ++reg) {
                float v = acc[mi][ni][reg] + bias;
                if (v < 0.f) v = 0.f;
                OUT[(size_t)(row + reg) * EMB + col] = v;
            }
        }
    }
}

// ---------------------------------------------------------------------------
// Kernel 3b (last-resort fallback): in-place scalar out-proj on d_out fp32.
// ---------------------------------------------------------------------------
__global__ __launch_bounds__(256) void out_proj_inplace(
    float* __restrict__ OUT, const float* __restrict__ Wo, const float* __restrict__ bo)
{
    __shared__ float Xs[8][EMB];
    const int t    = threadIdx.x;
    const int row0 = blockIdx.x * 8;
    {
        const float4* src = (const float4*)(OUT + (size_t)row0 * EMB);
        float4* dst = (float4*)&Xs[0][0];
        #pragma unroll
        for (int i = 0; i < 8; ++i) dst[i * 256 + t] = src[i * 256 + t];
    }
    __syncthreads();
    const int r  = t >> 5;
    const int j0 = (t & 31) * 2;
    const float* xrow = Xs[r];
    for (int jb = 0; jb < 16; ++jb) {
        const int j = jb * 64 + j0;
        float a0, a1;
        dot2_f32(xrow, Wo + j, EMB, a0, a1);
        a0 += bo[j];     if (a0 < 0.f) a0 = 0.f;
        a1 += bo[j + 1]; if (a1 < 0.f) a1 = 0.f;
        float* op = OUT + (size_t)(row0 + r) * EMB + j;
        op[0] = a0; op[1] = a1;
    }
}

// ---------------------------------------------------------------------------
extern "C" void kernel_launch(void* const* d_in, const int* in_sizes, int n_in,
                              void* d_out, int out_size, void* d_ws, size_t ws_size,
                              hipStream_t stream)
{
    const float* Xk = (const float*)d_in[0];
    const float* Xv = (const float*)d_in[1];
    const float* Xq = (const float*)d_in[2];
    const float* Wk = (const float*)d_in[3];
    const float* Wv = (const float*)d_in[4];
    const float* Wq = (const float*)d_in[5];
    const float* Wo = (const float*)d_in[6];
    const float* bo = (const float*)d_in[7];
    float* OUT = (float*)d_out;
    (void)in_sizes; (void)n_in; (void)out_size;

    const size_t SEGE = (size_t)BH * SEQ * DH;        // elems per Q/K/V/CTX segment
    const size_t SEGB = SEGE * sizeof(u16);           // 8 MB

    if (ws_size >= 4 * SEGB) {
        // full path: Q,K,V,CTX all staged bf16 in ws (32 MB)
        u16* Qw = (u16*)d_ws;
        u16* Kw = Qw + SEGE;
        u16* Vw = Kw + SEGE;
        u16* CT = Vw + SEGE;
        qkv_proj_mfma<<<dim3(32, HEADS, 3), 256, 0, stream>>>(Xk, Xv, Xq, Wk, Wv, Wq, Kw, Vw, Qw);
        attn_flash<true, true><<<dim3(SEQ / 64, BH), 256, 0, stream>>>(
            Xq, Wq, Qw, Kw, Vw, CT, nullptr);
        out_proj_mfma<<<dim3(32, EMB / 64), 256, 0, stream>>>(CT, Wo, bo, OUT);
    } else if (ws_size >= 3 * SEGB) {
        // proven 24 MB path: K,V,CTX in ws; Q projected inside attention
        u16* Kw = (u16*)d_ws;
        u16* Vw = Kw + SEGE;
        u16* CT = Vw + SEGE;
        qkv_proj_mfma<<<dim3(32, HEADS, 2), 256, 0, stream>>>(Xk, Xv, Xq, Wk, Wv, Wq, Kw, Vw, nullptr);
        attn_flash<false, true><<<dim3(SEQ / 64, BH), 256, 0, stream>>>(
            Xq, Wq, nullptr, Kw, Vw, CT, nullptr);
        out_proj_mfma<<<dim3(32, EMB / 64), 256, 0, stream>>>(CT, Wo, bo, OUT);
    } else {
        // 16 MB fallback: K,V in ws; CTX fp32 -> d_out; scalar in-place out-proj
        u16* Kw = (u16*)d_ws;
        u16* Vw = Kw + SEGE;
        qkv_proj_mfma<<<dim3(32, HEADS, 2), 256, 0, stream>>>(Xk, Xv, Xq, Wk, Wv, Wq, Kw, Vw, nullptr);
        attn_flash<false, false><<<dim3(SEQ / 64, BH), 256, 0, stream>>>(
            Xq, Wq, nullptr, Kw, Vw, nullptr, OUT);
        out_proj_inplace<<<dim3(BS / 8), 256, 0, stream>>>(OUT, Wo, bo);
    }
}

// Round 10
// 255.579 us; speedup vs baseline: 17.9354x; 1.4056x over previous
//
#include <hip/hip_runtime.h>
#include <hip/hip_bf16.h>

typedef unsigned short u16;
typedef unsigned int   u32;
typedef __attribute__((ext_vector_type(4))) float f32x4;
typedef __attribute__((ext_vector_type(8))) short bf16x8;

#define EMB   1024
#define SEQ   1024
#define HEADS 16
#define DH    64
#define BATCH 4
#define BH    64      // BATCH*HEADS
#define BS    4096    // BATCH*SEQ
#define LDP   72      // padded LDS row for attn kernels (144 B, 16B-aligned rows)
#define NEG_BIG (-1.0e30f)

__device__ __forceinline__ float b2f(u16 u){ return __uint_as_float(((u32)u) << 16); }
__device__ __forceinline__ u16 f2b(float f){
    u32 u = __float_as_uint(f);
    u32 r = u + 0x7fffu + ((u >> 16) & 1u);   // round-to-nearest-even
    return (u16)(r >> 16);
}
__device__ __forceinline__ void zero4(f32x4& v){ v[0]=0.f; v[1]=0.f; v[2]=0.f; v[3]=0.f; }
__device__ __forceinline__ ushort4 pk4(float a, float b, float c, float d){
    ushort4 p; p.x = f2b(a); p.y = f2b(b); p.z = f2b(c); p.w = f2b(d); return p;
}

// XOR-swizzled flat 128x64 bf16 tile: conflict-free b128 reads AND writes,
// 16B-aligned (padding would break alignment; swizzle doesn't).
__device__ __forceinline__ u16* tptr(u16* base, int row, int col /*mult of 8*/){
    const int phys = ((col >> 3) ^ (row & 7));
    return base + row * 64 + (phys << 3);
}

// fp32 dual-column dot (scalar fallback path only)
__device__ __forceinline__ void dot2_f32(const float* __restrict__ x,
                                         const float* __restrict__ w, const int ws,
                                         float& a0, float& a1)
{
    float s0 = 0.f, s1 = 0.f;
    for (int e = 0; e < EMB; e += 4) {
        const float4 xv = *(const float4*)(x + e);
        const float2 w0 = *(const float2*)(w + (size_t)(e + 0) * ws);
        const float2 w1 = *(const float2*)(w + (size_t)(e + 1) * ws);
        const float2 w2 = *(const float2*)(w + (size_t)(e + 2) * ws);
        const float2 w3 = *(const float2*)(w + (size_t)(e + 3) * ws);
        s0 += xv.x * w0.x; s1 += xv.x * w0.y;
        s0 += xv.y * w1.x; s1 += xv.y * w1.y;
        s0 += xv.z * w2.x; s1 += xv.z * w2.y;
        s0 += xv.w * w3.x; s1 += xv.w * w3.y;
    }
    a0 = s0; a1 = s1;
}

// ===========================================================================
// TIER A kernels
// ===========================================================================

// X fp32 -> bf16, 3 tensors. grid (4096, 3) x 256.
__global__ __launch_bounds__(256) void convert_x(
    const float* __restrict__ Xk, const float* __restrict__ Xv, const float* __restrict__ Xq,
    u16* __restrict__ XB)
{
    const int which = blockIdx.y;
    const float* __restrict__ src = (which == 0) ? Xk : (which == 1) ? Xv : Xq;
    const size_t off = (size_t)blockIdx.x * 1024 + threadIdx.x * 4;
    const float4 v = *(const float4*)(src + off);
    *(ushort4*)(XB + (size_t)which * 4194304 + off) = pk4(v.x, v.y, v.z, v.w);
}

// W[h][e][d] -> WT[h*64+d][e] bf16 (which<3); Wo[e][j] -> WoT[j][e] (which==3).
// grid (256, 4) x 256.
__global__ __launch_bounds__(256) void transpose_w(
    const float* __restrict__ Wk, const float* __restrict__ Wv, const float* __restrict__ Wq,
    const float* __restrict__ Wo, u16* __restrict__ WT, u16* __restrict__ WoT)
{
    __shared__ u16 T[64][LDP];
    const int which = blockIdx.y;
    const int bx = blockIdx.x, t = threadIdx.x;

    if (which < 3) {
        const float* __restrict__ W = (which == 0) ? Wk : (which == 1) ? Wv : Wq;
        const int h = bx >> 4, e0 = (bx & 15) * 64;
        #pragma unroll
        for (int i = 0; i < 16; ++i) {
            const int idx = i * 256 + t;
            const int e = idx >> 6, d = idx & 63;
            T[d][e] = f2b(W[(size_t)h * (EMB * DH) + (size_t)(e0 + e) * DH + d]);
        }
        __syncthreads();
        u16* dstb = WT + (size_t)which * (EMB * EMB / 16) * 16;   // which*1048576
        #pragma unroll
        for (int i = 0; i < 2; ++i) {
            const int idx = i * 256 + t;
            const int d = idx >> 3, e8 = (idx & 7) * 8;
            *(bf16x8*)(dstb + (size_t)(h * 64 + d) * EMB + e0 + e8) = *(const bf16x8*)&T[d][e8];
        }
    } else {
        const int j0 = (bx >> 4) * 64, e0 = (bx & 15) * 64;
        #pragma unroll
        for (int i = 0; i < 16; ++i) {
            const int idx = i * 256 + t;
            const int e = idx >> 6, d = idx & 63;
            T[d][e] = f2b(Wo[(size_t)(e0 + e) * EMB + j0 + d]);
        }
        __syncthreads();
        #pragma unroll
        for (int i = 0; i < 2; ++i) {
            const int idx = i * 256 + t;
            const int d = idx >> 3, e8 = (idx & 7) * 8;
            *(bf16x8*)(WoT + (size_t)(j0 + d) * EMB + e0 + e8) = *(const bf16x8*)&T[d][e8];
        }
    }
}

// Unified 128x128 bf16 GEMM, BK=64, XOR-swizzled tiles, 2x2 waves of 64x64.
// MODE 0: QKV projection (blockIdx.z = which; epilogue scatters K/V^T/Q).
// MODE 1: out-projection (A=CTX, B=WoT, +bias+ReLU -> fp32 OUT).
template<int MODE>
__global__ __launch_bounds__(256) void gemm128(
    const u16* __restrict__ XB, const u16* __restrict__ WT,
    u16* __restrict__ Qw, u16* __restrict__ Kw, u16* __restrict__ Vt,
    const float* __restrict__ bo, float* __restrict__ OUT)
{
    __shared__ u16 As[128 * 64];   // 16 KB swizzled
    __shared__ u16 Bs[128 * 64];   // 16 KB swizzled

    const int t = threadIdx.x;
    const int wave = t >> 6, lane = t & 63;
    const int quad = lane >> 4, l16 = lane & 15;
    const int wrow = wave >> 1, wcol = wave & 1;
    const int m0 = blockIdx.x * 128;
    const int n0 = blockIdx.y * 128;
    const int which = blockIdx.z;

    const u16* __restrict__ Ag = (MODE == 0) ? XB + (size_t)which * 4194304 : XB;
    const u16* __restrict__ Bg = (MODE == 0) ? WT + (size_t)which * 1048576 : WT;

    f32x4 acc[4][4];
    #pragma unroll
    for (int mi = 0; mi < 4; ++mi)
        #pragma unroll
        for (int ni = 0; ni < 4; ++ni) zero4(acc[mi][ni]);

    for (int k0 = 0; k0 < EMB; k0 += 64) {
        // stage A,B: 1024 chunks of 16B each; reg-buffer for MLP
        bf16x8 abuf[4], bbuf[4];
        #pragma unroll
        for (int i = 0; i < 4; ++i) {
            const int c = i * 256 + t;
            const int row = c >> 3, col8 = (c & 7) * 8;
            abuf[i] = *(const bf16x8*)(Ag + (size_t)(m0 + row) * EMB + k0 + col8);
            bbuf[i] = *(const bf16x8*)(Bg + (size_t)(n0 + row) * EMB + k0 + col8);
        }
        #pragma unroll
        for (int i = 0; i < 4; ++i) {
            const int c = i * 256 + t;
            const int row = c >> 3, col8 = (c & 7) * 8;
            *(bf16x8*)tptr(As, row, col8) = abuf[i];
            *(bf16x8*)tptr(Bs, row, col8) = bbuf[i];
        }
        __syncthreads();

        #pragma unroll
        for (int kb = 0; kb < 2; ++kb) {
            bf16x8 af[4], bf[4];
            #pragma unroll
            for (int mi = 0; mi < 4; ++mi)
                af[mi] = *(const bf16x8*)tptr(As, wrow * 64 + mi * 16 + l16, kb * 32 + quad * 8);
            #pragma unroll
            for (int ni = 0; ni < 4; ++ni)
                bf[ni] = *(const bf16x8*)tptr(Bs, wcol * 64 + ni * 16 + l16, kb * 32 + quad * 8);
            #pragma unroll
            for (int mi = 0; mi < 4; ++mi)
                #pragma unroll
                for (int ni = 0; ni < 4; ++ni)
                    acc[mi][ni] = __builtin_amdgcn_mfma_f32_16x16x32_bf16(af[mi], bf[ni], acc[mi][ni], 0, 0, 0);
        }
        __syncthreads();
    }

    // epilogue: C row r = m0+wrow*64+mi*16+quad*4+reg; col j = n0+wcol*64+ni*16+l16
    #pragma unroll
    for (int mi = 0; mi < 4; ++mi) {
        const int r = m0 + wrow * 64 + mi * 16 + quad * 4;
        #pragma unroll
        for (int ni = 0; ni < 4; ++ni) {
            const int j = n0 + wcol * 64 + ni * 16 + l16;
            if (MODE == 1) {
                const float bias = bo[j];
                #pragma unroll
                for (int reg = 0; reg < 4; ++reg) {
                    float v = acc[mi][ni][reg] + bias;
                    if (v < 0.f) v = 0.f;
                    OUT[(size_t)(r + reg) * EMB + j] = v;
                }
            } else {
                const int h = j >> 6, d = j & 63;
                const int b = r >> 10, s = r & (SEQ - 1);
                const int bh = b * HEADS + h;
                if (which == 1) {           // V^T [bh][d][s], 4 consecutive s
                    *(ushort4*)(Vt + ((size_t)bh * DH + d) * SEQ + s) =
                        pk4(acc[mi][ni][0], acc[mi][ni][1], acc[mi][ni][2], acc[mi][ni][3]);
                } else {                    // K or Q: [bh][s][d]
                    u16* dst = (which == 0) ? Kw : Qw;
                    #pragma unroll
                    for (int reg = 0; reg < 4; ++reg)
                        dst[((size_t)bh * SEQ + s + reg) * DH + d] = f2b(acc[mi][ni][reg]);
                }
            }
        }
    }
}

// ===========================================================================
// R9-proven kernels (fallback QKV + shared attention + out-proj)
// ===========================================================================

__global__ __launch_bounds__(256) void qkv_proj_mfma(
    const float* __restrict__ Xk, const float* __restrict__ Xv, const float* __restrict__ Xq,
    const float* __restrict__ Wk, const float* __restrict__ Wv, const float* __restrict__ Wq,
    u16* __restrict__ Kw, u16* __restrict__ Vw, u16* __restrict__ Qw)
{
    __shared__ u16 As[128][LDP];
    __shared__ u16 Bs[64][LDP];

    const int which = blockIdx.z;
    const float* __restrict__ X = (which == 0) ? Xk : (which == 1) ? Xv : Xq;
    const float* __restrict__ W = (which == 0) ? Wk : (which == 1) ? Wv : Wq;

    const int h    = blockIdx.y;
    const int m0   = blockIdx.x * 128;
    const int t    = threadIdx.x;
    const int wave = t >> 6, lane = t & 63;
    const int quad = lane >> 4, l16 = lane & 15;

    f32x4 acc[2][4];
    #pragma unroll
    for (int mi = 0; mi < 2; ++mi)
        #pragma unroll
        for (int ni = 0; ni < 4; ++ni) zero4(acc[mi][ni]);

    const size_t wbase = (size_t)h * EMB * DH;
    for (int k0 = 0; k0 < EMB; k0 += 64) {
        #pragma unroll
        for (int i = 0; i < 8; ++i) {
            const int idx = i * 256 + t;
            const int r = idx >> 4, c4 = (idx & 15) * 4;
            const float4 v = *(const float4*)(X + (size_t)(m0 + r) * EMB + k0 + c4);
            *(ushort4*)&As[r][c4] = pk4(v.x, v.y, v.z, v.w);
        }
        #pragma unroll
        for (int i = 0; i < 4; ++i) {
            const int d  = t & 63;
            const int e0 = (t >> 6) * 4 + i * 16;
            const float v0 = W[wbase + (size_t)(k0 + e0 + 0) * DH + d];
            const float v1 = W[wbase + (size_t)(k0 + e0 + 1) * DH + d];
            const float v2 = W[wbase + (size_t)(k0 + e0 + 2) * DH + d];
            const float v3 = W[wbase + (size_t)(k0 + e0 + 3) * DH + d];
            *(ushort4*)&Bs[d][e0] = pk4(v0, v1, v2, v3);
        }
        __syncthreads();

        #pragma unroll
        for (int kb = 0; kb < 2; ++kb) {
            bf16x8 bfr[4];
            #pragma unroll
            for (int ni = 0; ni < 4; ++ni)
                bfr[ni] = *(const bf16x8*)&Bs[ni * 16 + l16][kb * 32 + quad * 8];
            #pragma unroll
            for (int mi = 0; mi < 2; ++mi) {
                const bf16x8 af = *(const bf16x8*)&As[wave * 32 + mi * 16 + l16][kb * 32 + quad * 8];
                #pragma unroll
                for (int ni = 0; ni < 4; ++ni)
                    acc[mi][ni] = __builtin_amdgcn_mfma_f32_16x16x32_bf16(af, bfr[ni], acc[mi][ni], 0, 0, 0);
            }
        }
        __syncthreads();
    }

    const int b  = m0 >> 10;
    const int bh = b * HEADS + h;
    u16* __restrict__ RowDst = (which == 0) ? Kw : Qw;
    #pragma unroll
    for (int mi = 0; mi < 2; ++mi) {
        const int s_base = (m0 & (SEQ - 1)) + wave * 32 + mi * 16 + quad * 4;
        #pragma unroll
        for (int ni = 0; ni < 4; ++ni) {
            const int d = ni * 16 + l16;
            if (which != 1) {
                #pragma unroll
                for (int reg = 0; reg < 4; ++reg)
                    RowDst[((size_t)bh * SEQ + s_base + reg) * DH + d] = f2b(acc[mi][ni][reg]);
            } else {
                *(ushort4*)(Vw + ((size_t)bh * DH + d) * SEQ + s_base) =
                    pk4(acc[mi][ni][0], acc[mi][ni][1], acc[mi][ni][2], acc[mi][ni][3]);
            }
        }
    }
}

template<bool QWS, bool TOWS>
__global__ __launch_bounds__(256) void attn_flash(
    const float* __restrict__ Xq, const float* __restrict__ Wq,
    const u16* __restrict__ Qg, const u16* __restrict__ Kg, const u16* __restrict__ Vg,
    u16* __restrict__ CTXb, float* __restrict__ CTXf)
{
    __shared__ u16 Qs[64][LDP];
    union KVU {
        struct { u16 Ks[64][LDP]; u16 Vt[64][LDP]; } kv;
        struct { u16 Xs[64][LDP]; u16 WT[64][LDP]; } pr;
    };
    __shared__ KVU uu;
    __shared__ u16 Ps[64][LDP];

    const int t    = threadIdx.x;
    const int wave = t >> 6, lane = t & 63;
    const int quad = lane >> 4, l16 = lane & 15;
    const int qt = blockIdx.x, bh = blockIdx.y;
    const int b  = bh >> 4, h = bh & (HEADS - 1);
    const int q0 = qt * 64;

    if (QWS) {
        #pragma unroll
        for (int i = 0; i < 4; ++i) {
            const int idx = i * 256 + t;
            const int r = idx >> 4, c4 = (idx & 15) * 4;
            *(ushort4*)&Qs[r][c4] = *(const ushort4*)(Qg + ((size_t)bh * SEQ + q0 + r) * DH + c4);
        }
    } else {
        f32x4 qacc[4];
        #pragma unroll
        for (int ni = 0; ni < 4; ++ni) zero4(qacc[ni]);
        const size_t wbase = (size_t)h * EMB * DH;
        for (int k0 = 0; k0 < EMB; k0 += 64) {
            #pragma unroll
            for (int i = 0; i < 4; ++i) {
                const int idx = i * 256 + t;
                const int r = idx >> 4, c4 = (idx & 15) * 4;
                const float4 v = *(const float4*)(Xq + (size_t)(b * SEQ + q0 + r) * EMB + k0 + c4);
                *(ushort4*)&uu.pr.Xs[r][c4] = pk4(v.x, v.y, v.z, v.w);
            }
            #pragma unroll
            for (int i = 0; i < 4; ++i) {
                const int d  = t & 63;
                const int e0 = (t >> 6) * 4 + i * 16;
                const float v0 = Wq[wbase + (size_t)(k0 + e0 + 0) * DH + d];
                const float v1 = Wq[wbase + (size_t)(k0 + e0 + 1) * DH + d];
                const float v2 = Wq[wbase + (size_t)(k0 + e0 + 2) * DH + d];
                const float v3 = Wq[wbase + (size_t)(k0 + e0 + 3) * DH + d];
                *(ushort4*)&uu.pr.WT[d][e0] = pk4(v0, v1, v2, v3);
            }
            __syncthreads();
            #pragma unroll
            for (int kb = 0; kb < 2; ++kb) {
                const bf16x8 af = *(const bf16x8*)&uu.pr.Xs[wave * 16 + l16][kb * 32 + quad * 8];
                #pragma unroll
                for (int ni = 0; ni < 4; ++ni) {
                    const bf16x8 bf = *(const bf16x8*)&uu.pr.WT[ni * 16 + l16][kb * 32 + quad * 8];
                    qacc[ni] = __builtin_amdgcn_mfma_f32_16x16x32_bf16(af, bf, qacc[ni], 0, 0, 0);
                }
            }
            __syncthreads();
        }
        #pragma unroll
        for (int ni = 0; ni < 4; ++ni)
            #pragma unroll
            for (int reg = 0; reg < 4; ++reg)
                Qs[wave * 16 + quad * 4 + reg][ni * 16 + l16] = f2b(qacc[ni][reg]);
    }

    float m[4], l[4];
    #pragma unroll
    for (int reg = 0; reg < 4; ++reg) { m[reg] = NEG_BIG; l[reg] = 0.f; }
    f32x4 oacc[4];
    #pragma unroll
    for (int ni = 0; ni < 4; ++ni) zero4(oacc[ni]);
    __syncthreads();

    for (int c = 0; c <= qt; ++c) {
        const int k0 = c * 64;

        #pragma unroll
        for (int i = 0; i < 4; ++i) {
            const int idx = i * 256 + t;
            const int r = idx >> 4, c4 = (idx & 15) * 4;
            *(ushort4*)&uu.kv.Ks[r][c4] = *(const ushort4*)(Kg + ((size_t)bh * SEQ + k0 + r) * DH + c4);
        }
        #pragma unroll
        for (int i = 0; i < 4; ++i) {
            const int idx = i * 256 + t;
            const int r = idx >> 4, c4 = (idx & 15) * 4;
            *(ushort4*)&uu.kv.Vt[r][c4] = *(const ushort4*)(Vg + ((size_t)bh * DH + r) * SEQ + k0 + c4);
        }
        __syncthreads();

        f32x4 sacc[4];
        #pragma unroll
        for (int ni = 0; ni < 4; ++ni) zero4(sacc[ni]);
        #pragma unroll
        for (int kb = 0; kb < 2; ++kb) {
            const bf16x8 af = *(const bf16x8*)&Qs[wave * 16 + l16][kb * 32 + quad * 8];
            #pragma unroll
            for (int ni = 0; ni < 4; ++ni) {
                const bf16x8 bf = *(const bf16x8*)&uu.kv.Ks[ni * 16 + l16][kb * 32 + quad * 8];
                sacc[ni] = __builtin_amdgcn_mfma_f32_16x16x32_bf16(af, bf, sacc[ni], 0, 0, 0);
            }
        }

        const bool diag = (c == qt);
        #pragma unroll
        for (int reg = 0; reg < 4; ++reg) {
            const int rloc = quad * 4 + reg;
            float sv[4];
            #pragma unroll
            for (int ni = 0; ni < 4; ++ni) {
                float s = sacc[ni][reg] * 0.03125f;
                if (diag && (ni * 16 + l16 > wave * 16 + rloc)) s = NEG_BIG;
                sv[ni] = s;
            }
            float mx = fmaxf(fmaxf(sv[0], sv[1]), fmaxf(sv[2], sv[3]));
            mx = fmaxf(mx, m[reg]);
            #pragma unroll
            for (int off = 1; off < 16; off <<= 1) mx = fmaxf(mx, __shfl_xor(mx, off));
            const float alpha = __expf(m[reg] - mx);
            float rs = 0.f;
            #pragma unroll
            for (int ni = 0; ni < 4; ++ni) {
                const float p = __expf(sv[ni] - mx);
                Ps[wave * 16 + rloc][ni * 16 + l16] = f2b(p);
                rs += p;
            }
            #pragma unroll
            for (int off = 1; off < 16; off <<= 1) rs += __shfl_xor(rs, off);
            l[reg] = l[reg] * alpha + rs;
            m[reg] = mx;
            #pragma unroll
            for (int ni = 0; ni < 4; ++ni) oacc[ni][reg] *= alpha;
        }
        __syncthreads();

        #pragma unroll
        for (int kb = 0; kb < 2; ++kb) {
            const bf16x8 af = *(const bf16x8*)&Ps[wave * 16 + l16][kb * 32 + quad * 8];
            #pragma unroll
            for (int ni = 0; ni < 4; ++ni) {
                const bf16x8 bf = *(const bf16x8*)&uu.kv.Vt[ni * 16 + l16][kb * 32 + quad * 8];
                oacc[ni] = __builtin_amdgcn_mfma_f32_16x16x32_bf16(af, bf, oacc[ni], 0, 0, 0);
            }
        }
        __syncthreads();
    }

    float il[4];
    #pragma unroll
    for (int reg = 0; reg < 4; ++reg) il[reg] = 1.f / l[reg];
    #pragma unroll
    for (int ni = 0; ni < 4; ++ni) {
        const int d = ni * 16 + l16;
        #pragma unroll
        for (int reg = 0; reg < 4; ++reg) {
            const int q = wave * 16 + quad * 4 + reg;
            const float val = oacc[ni][reg] * il[reg];
            const size_t off = ((size_t)(b * SEQ + q0 + q)) * EMB + h * DH + d;
            if (TOWS) CTXb[off] = f2b(val);
            else      CTXf[off] = val;
        }
    }
}

__global__ __launch_bounds__(256) void out_proj_mfma(
    const u16* __restrict__ CTXb, const float* __restrict__ Wo,
    const float* __restrict__ bo, float* __restrict__ OUT)
{
    __shared__ u16 As[128][LDP];
    __shared__ u16 Bs[64][LDP];

    const int m0 = blockIdx.x * 128;
    const int n0 = blockIdx.y * 64;
    const int t = threadIdx.x;
    const int wave = t >> 6, lane = t & 63;
    const int quad = lane >> 4, l16 = lane & 15;

    f32x4 acc[2][4];
    #pragma unroll
    for (int mi = 0; mi < 2; ++mi)
        #pragma unroll
        for (int ni = 0; ni < 4; ++ni) zero4(acc[mi][ni]);

    for (int k0 = 0; k0 < EMB; k0 += 64) {
        #pragma unroll
        for (int i = 0; i < 8; ++i) {
            const int idx = i * 256 + t;
            const int r = idx >> 4, c4 = (idx & 15) * 4;
            *(ushort4*)&As[r][c4] = *(const ushort4*)(CTXb + (size_t)(m0 + r) * EMB + k0 + c4);
        }
        #pragma unroll
        for (int i = 0; i < 4; ++i) {
            const int d  = t & 63;
            const int e0 = (t >> 6) * 4 + i * 16;
            const float v0 = Wo[(size_t)(k0 + e0 + 0) * EMB + n0 + d];
            const float v1 = Wo[(size_t)(k0 + e0 + 1) * EMB + n0 + d];
            const float v2 = Wo[(size_t)(k0 + e0 + 2) * EMB + n0 + d];
            const float v3 = Wo[(size_t)(k0 + e0 + 3) * EMB + n0 + d];
            *(ushort4*)&Bs[d][e0] = pk4(v0, v1, v2, v3);
        }
        __syncthreads();
        #pragma unroll
        for (int kb = 0; kb < 2; ++kb) {
            bf16x8 bfr[4];
            #pragma unroll
            for (int ni = 0; ni < 4; ++ni)
                bfr[ni] = *(const bf16x8*)&Bs[ni * 16 + l16][kb * 32 + quad * 8];
            #pragma unroll
            for (int mi = 0; mi < 2; ++mi) {
                const bf16x8 af = *(const bf16x8*)&As[wave * 32 + mi * 16 + l16][kb * 32 + quad * 8];
                #pragma unroll
                for (int ni = 0; ni < 4; ++ni)
                    acc[mi][ni] = __builtin_amdgcn_mfma_f32_16x16x32_bf16(af, bfr[ni], acc[mi][ni], 0, 0, 0);
            }
        }
        __syncthreads();
    }

    #pragma unroll
    for (int mi = 0; mi < 2; ++mi) {
        const int row = m0 + wave * 32 + mi * 16 + quad * 4;
        #pragma unroll
        for (int ni = 0; ni < 4; ++ni) {
            const int col = n0 + ni * 16 + l16;
            const float bias = bo[col];
            #pragma unroll
            for (int reg = 0; reg < 4; ++reg) {
                float v = acc[mi][ni][reg] + bias;
                if (v < 0.f) v = 0.f;
                OUT[(size_t)(row + reg) * EMB + col] = v;
            }
        }
    }
}

__global__ __launch_bounds__(256) void out_proj_inplace(
    float* __restrict__ OUT, const float* __restrict__ Wo, const float* __restrict__ bo)
{
    __shared__ float Xs[8][EMB];
    const int t    = threadIdx.x;
    const int row0 = blockIdx.x * 8;
    {
        const float4* src = (const float4*)(OUT + (size_t)row0 * EMB);
        float4* dst = (float4*)&Xs[0][0];
        #pragma unroll
        for (int i = 0; i < 8; ++i) dst[i * 256 + t] = src[i * 256 + t];
    }
    __syncthreads();
    const int r  = t >> 5;
    const int j0 = (t & 31) * 2;
    const float* xrow = Xs[r];
    for (int jb = 0; jb < 16; ++jb) {
        const int j = jb * 64 + j0;
        float a0, a1;
        dot2_f32(xrow, Wo + j, EMB, a0, a1);
        a0 += bo[j];     if (a0 < 0.f) a0 = 0.f;
        a1 += bo[j + 1]; if (a1 < 0.f) a1 = 0.f;
        float* op = OUT + (size_t)(row0 + r) * EMB + j;
        op[0] = a0; op[1] = a1;
    }
}

// ---------------------------------------------------------------------------
extern "C" void kernel_launch(void* const* d_in, const int* in_sizes, int n_in,
                              void* d_out, int out_size, void* d_ws, size_t ws_size,
                              hipStream_t stream)
{
    const float* Xk = (const float*)d_in[0];
    const float* Xv = (const float*)d_in[1];
    const float* Xq = (const float*)d_in[2];
    const float* Wk = (const float*)d_in[3];
    const float* Wv = (const float*)d_in[4];
    const float* Wq = (const float*)d_in[5];
    const float* Wo = (const float*)d_in[6];
    const float* bo = (const float*)d_in[7];
    float* OUT = (float*)d_out;
    (void)in_sizes; (void)n_in; (void)out_size;

    const size_t SEGE = (size_t)BH * SEQ * DH;        // 4,194,304 elems
    const size_t SEGB = SEGE * sizeof(u16);           // 8 MB

    // Tier A ws layout (u16 elems):
    //   XB (3*4M, aliased by CTX after gemm_qkv) | WT (3*1M) | WoT (1M) | Qw | Kw | Vt
    const size_t XB_OFF  = 0;
    const size_t WT_OFF  = 3 * SEGE;                  // 12,582,912
    const size_t WOT_OFF = WT_OFF + 3 * (EMB * EMB / 64) * 64;  // +3*1,048,576
    const size_t QW_OFF  = WOT_OFF + (size_t)EMB * EMB;
    const size_t KW_OFF  = QW_OFF + SEGE;
    const size_t VT_OFF  = KW_OFF + SEGE;
    const size_t TIER_A_BYTES = (VT_OFF + SEGE) * sizeof(u16);  // 58,720,256

    if (ws_size >= TIER_A_BYTES) {
        u16* W16 = (u16*)d_ws;
        u16* XB  = W16 + XB_OFF;
        u16* WT  = W16 + WT_OFF;
        u16* WoT = W16 + WOT_OFF;
        u16* Qw  = W16 + QW_OFF;
        u16* Kw  = W16 + KW_OFF;
        u16* Vt  = W16 + VT_OFF;
        u16* CTX = XB;                                // alias (XB dead after gemm_qkv)

        convert_x<<<dim3(4096, 3), 256, 0, stream>>>(Xk, Xv, Xq, XB);
        transpose_w<<<dim3(256, 4), 256, 0, stream>>>(Wk, Wv, Wq, Wo, WT, WoT);
        gemm128<0><<<dim3(32, 8, 3), 256, 0, stream>>>(XB, WT, Qw, Kw, Vt, nullptr, nullptr);
        attn_flash<true, true><<<dim3(SEQ / 64, BH), 256, 0, stream>>>(
            Xq, Wq, Qw, Kw, Vt, CTX, nullptr);
        gemm128<1><<<dim3(32, 8, 1), 256, 0, stream>>>(CTX, WoT, nullptr, nullptr, nullptr, bo, OUT);
    } else if (ws_size >= 4 * SEGB) {
        u16* Qw = (u16*)d_ws;
        u16* Kw = Qw + SEGE;
        u16* Vw = Kw + SEGE;
        u16* CT = Vw + SEGE;
        qkv_proj_mfma<<<dim3(32, HEADS, 3), 256, 0, stream>>>(Xk, Xv, Xq, Wk, Wv, Wq, Kw, Vw, Qw);
        attn_flash<true, true><<<dim3(SEQ / 64, BH), 256, 0, stream>>>(
            Xq, Wq, Qw, Kw, Vw, CT, nullptr);
        out_proj_mfma<<<dim3(32, EMB / 64), 256, 0, stream>>>(CT, Wo, bo, OUT);
    } else if (ws_size >= 3 * SEGB) {
        u16* Kw = (u16*)d_ws;
        u16* Vw = Kw + SEGE;
        u16* CT = Vw + SEGE;
        qkv_proj_mfma<<<dim3(32, HEADS, 2), 256, 0, stream>>>(Xk, Xv, Xq, Wk, Wv, Wq, Kw, Vw, nullptr);
        attn_flash<false, true><<<dim3(SEQ / 64, BH), 256, 0, stream>>>(
            Xq, Wq, nullptr, Kw, Vw, CT, nullptr);
        out_proj_mfma<<<dim3(32, EMB / 64), 256, 0, stream>>>(CT, Wo, bo, OUT);
    } else {
        u16* Kw = (u16*)d_ws;
        u16* Vw = Kw + SEGE;
        qkv_proj_mfma<<<dim3(32, HEADS, 2), 256, 0, stream>>>(Xk, Xv, Xq, Wk, Wv, Wq, Kw, Vw, nullptr);
        attn_flash<false, false><<<dim3(SEQ / 64, BH), 256, 0, stream>>>(
            Xq, Wq, nullptr, Kw, Vw, nullptr, OUT);
        out_proj_inplace<<<dim3(BS / 8), 256, 0, stream>>>(OUT, Wo, bo);
    }
}